// Round 3
// baseline (542.447 us; speedup 1.0000x reference)
//
#include <hip/hip_runtime.h>
#include <stdint.h>

#define DEV __device__ __forceinline__

// ---------- problem constants ----------
#define BP 96
#define NTOK 196
#define DIM 512
#define HID 256
#define NS 500
#define TOPK 49
#define ROWS (BP * NTOK)          // 18816
#define RB 16                     // rows per fused block

// ---------- math helpers ----------
DEV double gelu64(double v) {
  return 0.5 * v * (1.0 + erf(v * 0.7071067811865476));
}

// Threefry-2x32, 20 rounds, key = (0, 1)  (jax.random.key(1))
DEV void threefry2x32(uint32_t x0, uint32_t x1, uint32_t& o0, uint32_t& o1) {
  const uint32_t k0 = 0u, k1 = 1u;
  const uint32_t k2 = 0x1BD11BDAu ^ k0 ^ k1;
  x0 += k0; x1 += k1;
#define TF_R(r) { x0 += x1; x1 = (x1 << (r)) | (x1 >> (32 - (r))); x1 ^= x0; }
  TF_R(13) TF_R(15) TF_R(26) TF_R(6)
  x0 += k1; x1 += k2 + 1u;
  TF_R(17) TF_R(29) TF_R(16) TF_R(24)
  x0 += k2; x1 += k0 + 2u;
  TF_R(13) TF_R(15) TF_R(26) TF_R(6)
  x0 += k0; x1 += k1 + 3u;
  TF_R(17) TF_R(29) TF_R(16) TF_R(24)
  x0 += k1; x1 += k2 + 4u;
  TF_R(13) TF_R(15) TF_R(26) TF_R(6)
  x0 += k2; x1 += k0 + 5u;
#undef TF_R
  o0 = x0; o1 = x1;
}

// XLA ErfInv32 (Giles polynomial)
DEV float erfinv_xla(float x) {
  float w = -log1pf(-x * x);
  float ws = w - 2.5f;
  float wl = sqrtf(w) - 3.0f;
  float ps = 2.81022636e-08f;
  ps = fmaf(ps, ws, 3.43273939e-07f);
  ps = fmaf(ps, ws, -3.5233877e-06f);
  ps = fmaf(ps, ws, -4.39150654e-06f);
  ps = fmaf(ps, ws, 0.00021858087f);
  ps = fmaf(ps, ws, -0.00125372503f);
  ps = fmaf(ps, ws, -0.00417768164f);
  ps = fmaf(ps, ws, 0.246640727f);
  ps = fmaf(ps, ws, 1.50140941f);
  float pl = -0.000200214257f;
  pl = fmaf(pl, wl, 0.000100950558f);
  pl = fmaf(pl, wl, 0.00134934322f);
  pl = fmaf(pl, wl, -0.00367342844f);
  pl = fmaf(pl, wl, 0.00573950773f);
  pl = fmaf(pl, wl, -0.0076224613f);
  pl = fmaf(pl, wl, 0.00943887047f);
  pl = fmaf(pl, wl, 1.00167406f);
  pl = fmaf(pl, wl, 2.83297682f);
  return (w < 5.0f ? ps : pl) * x;
}

// jax-f32-faithful N(0,1) noise at flat index g of the (96,500,196) tensor.
// PARTITIONABLE threefry (jax >= 0.4.36 default): counter = (hi32(g), lo32(g)),
// 32-bit draw = o0 ^ o1.
DEV float noise_at(unsigned g) {
  unsigned o0, o1;
  threefry2x32(0u, g, o0, o1);
  unsigned bits = o0 ^ o1;
  float f = __uint_as_float((bits >> 9) | 0x3f800000u) - 1.0f;
  float u = f * 2.0f - 0.99999994f;   // (hi-lo) rounds to exactly 2.0f
  u = fmaxf(-0.99999994f, u);
  return 1.41421356f * erfinv_xla(u);
}

// ---------- K0: guidance constants c1,c2 (96 x 256 each, f64) ----------
__global__ __launch_bounds__(256) void k_glob(
    const float* __restrict__ gf, const float* __restrict__ gs,
    const float* __restrict__ lng, const float* __restrict__ lnb,
    const float* __restrict__ Wgd, const float* __restrict__ Wout1,
    double* __restrict__ cout) {
  int bq = blockIdx.x >> 1, which = blockIdx.x & 1;
  const float* row = which ? (gs + (size_t)(bq / 12) * DIM) : (gf + (size_t)bq * DIM);
  __shared__ double lx[DIM];
  __shared__ double sg[HID];
  __shared__ double sred[8];
  int tid = threadIdx.x, lane = tid & 63, wv = tid >> 6;
  double v0 = (double)row[tid], v1 = (double)row[tid + 256];
  double s = v0 + v1, q = v0 * v0 + v1 * v1;
  #pragma unroll
  for (int m = 1; m < 64; m <<= 1) { s += __shfl_xor(s, m); q += __shfl_xor(q, m); }
  if (lane == 0) { sred[wv * 2] = s; sred[wv * 2 + 1] = q; }
  __syncthreads();
  double ts = sred[0] + sred[2] + sred[4] + sred[6];
  double tq = sred[1] + sred[3] + sred[5] + sred[7];
  double mean = ts / 512.0;
  double var = tq / 512.0 - mean * mean;
  double rs = 1.0 / sqrt(var + 1e-5);
  lx[tid]       = (v0 - mean) * rs * (double)lng[tid] + (double)lnb[tid];
  lx[tid + 256] = (v1 - mean) * rs * (double)lng[tid + 256] + (double)lnb[tid + 256];
  __syncthreads();
  double acc = 0.0;
  for (int d = 0; d < DIM; ++d) acc += lx[d] * (double)Wgd[(size_t)d * HID + tid];
  sg[tid] = gelu64(acc);
  __syncthreads();
  double c = 0.0;
  for (int j = 0; j < HID; ++j) c += sg[j] * (double)Wout1[(size_t)(HID + j) * HID + tid];
  cout[((size_t)which * BP + bq) * HID + tid] = c;
}

// ---------- K1: fused LN -> GEMM1(gelu) -> GEMM2 -> epilogue -> scores (f64) ----------
__global__ __launch_bounds__(256) void k_fused(
    const float* __restrict__ x,
    const float* __restrict__ g_in, const float* __restrict__ b_in,
    const float* __restrict__ Win, const float* __restrict__ W1,
    const float* __restrict__ W2,
    const double* __restrict__ c1, const double* __restrict__ c2,
    double* __restrict__ scores) {
  __shared__ __align__(16) char smem[RB * DIM * 4];   // 32 KB union: xs / loc / red
  __shared__ double stat[RB][2];
  float (*xs)[DIM] = (float(*)[DIM])smem;
  double (*loc)[HID] = (double(*)[HID])smem;
  double (*red)[HID] = (double(*)[HID])smem;

  const int tid = threadIdx.x, lane = tid & 63, wv = tid >> 6;
  const int gr0 = blockIdx.x * RB;

  // ---- stage x rows (f32) ----
  #pragma unroll
  for (int i = 0; i < 8; ++i) {
    int j = tid + i * 256;              // float4 index, 2048 total
    int row = j >> 7, c4 = (j & 127) << 2;
    *(float4*)&xs[row][c4] = *(const float4*)(x + (size_t)(gr0 + row) * DIM + c4);
  }
  __syncthreads();

  // ---- per-row LN stats (f64) ----
  #pragma unroll
  for (int rr = 0; rr < 4; ++rr) {
    int row = wv * 4 + rr;
    double s = 0.0, q = 0.0;
    #pragma unroll
    for (int e = 0; e < 8; ++e) {
      double v = (double)xs[row][lane + 64 * e];
      s += v; q += v * v;
    }
    #pragma unroll
    for (int m = 1; m < 64; m <<= 1) { s += __shfl_xor(s, m); q += __shfl_xor(q, m); }
    if (lane == 0) {
      double mean = s / 512.0;
      double var = q / 512.0 - mean * mean;
      stat[row][0] = mean;
      stat[row][1] = 1.0 / sqrt(var + 1e-5);
    }
  }
  __syncthreads();

  // ---- phase B: S1[row] = sum_d x[row][d] * (g[d]*Win[d][tid]); gw, bw alongside ----
  double acc[RB];
  #pragma unroll
  for (int r = 0; r < RB; ++r) acc[r] = 0.0;
  double gw = 0.0, bw = 0.0;
  for (int d0 = 0; d0 < DIM; d0 += 4) {
    float4 xv[RB];
    #pragma unroll
    for (int r = 0; r < RB; ++r) xv[r] = *(const float4*)&xs[r][d0];
    #pragma unroll
    for (int e = 0; e < 4; ++e) {
      int d = d0 + e;
      double wr = (double)Win[(size_t)d * HID + tid];
      double wg = wr * (double)g_in[d];
      gw += wg;
      bw += (double)b_in[d] * wr;
      #pragma unroll
      for (int r = 0; r < RB; ++r) {
        float xe = (e == 0) ? xv[r].x : (e == 1) ? xv[r].y : (e == 2) ? xv[r].z : xv[r].w;
        acc[r] += (double)xe * wg;
      }
    }
  }
  __syncthreads();   // all xs reads done before overwrite

  // ---- local = gelu(r*S1 - r*m*gw + bw) into union (f64) ----
  #pragma unroll
  for (int r = 0; r < RB; ++r) {
    double mn = stat[r][0], rs = stat[r][1];
    loc[r][tid] = gelu64(rs * acc[r] - rs * mn * gw + bw);
  }
  __syncthreads();

  // ---- phase C: U[row] = sum_j local[row][j] * W1[j][tid] ----
  double acc2[RB];
  #pragma unroll
  for (int r = 0; r < RB; ++r) acc2[r] = 0.0;
  for (int j0 = 0; j0 < HID; j0 += 2) {
    double2 lv[RB];
    #pragma unroll
    for (int r = 0; r < RB; ++r) lv[r] = *(const double2*)&loc[r][j0];
    #pragma unroll
    for (int e = 0; e < 2; ++e) {
      double w1 = (double)W1[(size_t)(j0 + e) * HID + tid];
      #pragma unroll
      for (int r = 0; r < RB; ++r) acc2[r] += ((e == 0) ? lv[r].x : lv[r].y) * w1;
    }
  }
  __syncthreads();   // loc reads done before red overwrite

  // ---- phase D: s1/s2 reductions and scores ----
  double w2 = (double)W2[tid];
  #pragma unroll
  for (int r = 0; r < RB; ++r) {
    int bfr = (gr0 + r) / NTOK;
    red[r][tid] = gelu64(acc2[r] + c1[(size_t)bfr * HID + tid]) * w2;
  }
  __syncthreads();
  double s1v[4];
  #pragma unroll
  for (int rr = 0; rr < 4; ++rr) {
    int row = wv * 4 + rr;
    double s = red[row][lane] + red[row][lane + 64] + red[row][lane + 128] + red[row][lane + 192];
    #pragma unroll
    for (int m = 1; m < 64; m <<= 1) s += __shfl_xor(s, m);
    s1v[rr] = s;
  }
  __syncthreads();
  #pragma unroll
  for (int r = 0; r < RB; ++r) {
    int bfr = (gr0 + r) / NTOK;
    red[r][tid] = gelu64(acc2[r] + c2[(size_t)bfr * HID + tid]) * w2;
  }
  __syncthreads();
  #pragma unroll
  for (int rr = 0; rr < 4; ++rr) {
    int row = wv * 4 + rr;
    double s = red[row][lane] + red[row][lane + 64] + red[row][lane + 128] + red[row][lane + 192];
    #pragma unroll
    for (int m = 1; m < 64; m <<= 1) s += __shfl_xor(s, m);
    if (lane == 0) scores[gr0 + row] = tanh(s1v[rr]) + tanh(s);
  }
}

// ---------- K2: perturbed top-k scatter, f64 keys, int counts ----------
__global__ __launch_bounds__(256) void k_topk(const double* __restrict__ scores,
                                              int* __restrict__ cnt) {
  int sid = blockIdx.x * 4 + (threadIdx.x >> 6);  // 0..47999
  int lane = threadIdx.x & 63;
  int b = sid / NS;
  unsigned long long key[4];
  #pragma unroll
  for (int c = 0; c < 4; ++c) {
    int j = c * 64 + lane;
    if (j < NTOK) {
      float n = noise_at((unsigned)sid * 196u + (unsigned)j);
      float sn = 0.05f * n;                       // f32 mul (matches SIGMA*noise in f32)
      double pv = scores[b * NTOK + j] + (double)sn;
      unsigned long long ub = (unsigned long long)__double_as_longlong(pv);
      key[c] = (ub >> 63) ? ~ub : (ub | 0x8000000000000000ull);
    } else {
      key[c] = 0ull;
    }
  }
  // binary search for the 49th-largest 64-bit key
  unsigned long long prefix = 0ull;
  for (int bit = 63; bit >= 0; --bit) {
    unsigned long long t = prefix | (1ull << bit);
    int cn = 0;
    #pragma unroll
    for (int c = 0; c < 4; ++c) cn += __popcll(__ballot(key[c] >= t));
    if (cn >= TOPK) prefix = t;
  }
  unsigned long long mE[4];
  int cntG = 0;
  #pragma unroll
  for (int c = 0; c < 4; ++c) {
    cntG += __popcll(__ballot(key[c] > prefix));
    mE[c] = __ballot(key[c] == prefix);
  }
  int need = TOPK - cntG;                      // >=1; ties -> lowest index (stable top_k)
  unsigned long long lt = (1ull << lane) - 1ull;
  bool sel[4];
  #pragma unroll
  for (int c = 0; c < 4; ++c) {
    int er = 0;
    for (int cc = 0; cc < c; ++cc) er += __popcll(mE[cc]);
    er += __popcll(mE[c] & lt);
    sel[c] = (key[c] > prefix) || ((key[c] == prefix) && (er < need));
  }
  unsigned long long mS[4];
  #pragma unroll
  for (int c = 0; c < 4; ++c) mS[c] = __ballot(sel[c]);
  int base = 0;
  #pragma unroll
  for (int c = 0; c < 4; ++c) {
    if (sel[c]) {
      int rank = base + __popcll(mS[c] & lt);
      int j = c * 64 + lane;
      atomicAdd(&cnt[((size_t)b * TOPK + rank) * NTOK + j], 1);
    }
    base += __popcll(mS[c]);
  }
}

// ---------- K3: out[b,k,:] = sum_l (cnt/500) * x[b,l,:]  (f64 accum) ----------
__global__ __launch_bounds__(128) void k_out(const float* __restrict__ x,
                                             const int* __restrict__ cnt,
                                             float* __restrict__ out) {
  int bk = blockIdx.x;          // 0..96*49-1
  int b = bk / TOPK;
  __shared__ double sw[NTOK];
  for (int l = threadIdx.x; l < NTOK; l += 128)
    sw[l] = (double)cnt[(size_t)bk * NTOK + l] * 0.002;
  __syncthreads();
  int d = threadIdx.x * 4;
  double a0 = 0, a1 = 0, a2 = 0, a3 = 0;
  for (int l = 0; l < NTOK; ++l) {
    double w = sw[l];
    if (w != 0.0) {
      float4 xv = *(const float4*)(x + ((size_t)(b * NTOK + l)) * DIM + d);
      a0 += w * (double)xv.x; a1 += w * (double)xv.y;
      a2 += w * (double)xv.z; a3 += w * (double)xv.w;
    }
  }
  float4 o = {(float)a0, (float)a1, (float)a2, (float)a3};
  *(float4*)(out + (size_t)bk * DIM + d) = o;
}

// ---------- launcher ----------
extern "C" void kernel_launch(void* const* d_in, const int* in_sizes, int n_in,
                              void* d_out, int out_size, void* d_ws, size_t ws_size,
                              hipStream_t stream) {
  const float* x       = (const float*)d_in[0];
  const float* gf      = (const float*)d_in[1];
  const float* gs      = (const float*)d_in[2];
  const float* ln_in_g = (const float*)d_in[3];
  const float* ln_in_b = (const float*)d_in[4];
  const float* W_in    = (const float*)d_in[5];
  const float* ln_gd_g = (const float*)d_in[6];
  const float* ln_gd_b = (const float*)d_in[7];
  const float* W_gd    = (const float*)d_in[8];
  const float* W_out1  = (const float*)d_in[9];
  const float* W_out2  = (const float*)d_in[10];
  float* out = (float*)d_out;

  // ws layout: c1 (24576 d) | c2 (24576 d) | scores (18816 d) | cnt (921984 int)
  double* c1     = (double*)d_ws;
  double* c2     = c1 + 24576;
  double* scores = c2 + 24576;
  int*    cnt    = (int*)(scores + ROWS);

  k_glob<<<192, 256, 0, stream>>>(gf, gs, ln_gd_g, ln_gd_b, W_gd, W_out1, c1);
  k_fused<<<ROWS / RB, 256, 0, stream>>>(x, ln_in_g, ln_in_b, W_in, W_out1, W_out2,
                                         c1, c2, scores);
  hipMemsetAsync(cnt, 0, (size_t)BP * TOPK * NTOK * sizeof(int), stream);
  k_topk<<<(BP * NS) / 4, 256, 0, stream>>>(scores, cnt);
  k_out<<<BP * TOPK, 128, 0, stream>>>(x, cnt, out);
}

// Round 4
// 507.279 us; speedup vs baseline: 1.0693x; 1.0693x over previous
//
#include <hip/hip_runtime.h>
#include <stdint.h>

#define DEV __device__ __forceinline__

// ---------- problem constants ----------
#define BP 96
#define NTOK 196
#define DIM 512
#define HID 256
#define NS 500
#define TOPK 49
#define ROWS (BP * NTOK)          // 18816
#define RB 16                     // rows per fused block

// ---------- math helpers ----------
DEV float gelu32(float v) {
  return 0.5f * v * (1.0f + erff(v * 0.70710678f));
}

// Threefry-2x32, 20 rounds, key = (0, 1)  (jax.random.key(1))
DEV void threefry2x32(uint32_t x0, uint32_t x1, uint32_t& o0, uint32_t& o1) {
  const uint32_t k0 = 0u, k1 = 1u;
  const uint32_t k2 = 0x1BD11BDAu ^ k0 ^ k1;
  x0 += k0; x1 += k1;
#define TF_R(r) { x0 += x1; x1 = (x1 << (r)) | (x1 >> (32 - (r))); x1 ^= x0; }
  TF_R(13) TF_R(15) TF_R(26) TF_R(6)
  x0 += k1; x1 += k2 + 1u;
  TF_R(17) TF_R(29) TF_R(16) TF_R(24)
  x0 += k2; x1 += k0 + 2u;
  TF_R(13) TF_R(15) TF_R(26) TF_R(6)
  x0 += k0; x1 += k1 + 3u;
  TF_R(17) TF_R(29) TF_R(16) TF_R(24)
  x0 += k1; x1 += k2 + 4u;
  TF_R(13) TF_R(15) TF_R(26) TF_R(6)
  x0 += k2; x1 += k0 + 5u;
#undef TF_R
  o0 = x0; o1 = x1;
}

// XLA ErfInv32 (Giles polynomial)
DEV float erfinv_xla(float x) {
  float w = -log1pf(-x * x);
  float ws = w - 2.5f;
  float wl = sqrtf(w) - 3.0f;
  float ps = 2.81022636e-08f;
  ps = fmaf(ps, ws, 3.43273939e-07f);
  ps = fmaf(ps, ws, -3.5233877e-06f);
  ps = fmaf(ps, ws, -4.39150654e-06f);
  ps = fmaf(ps, ws, 0.00021858087f);
  ps = fmaf(ps, ws, -0.00125372503f);
  ps = fmaf(ps, ws, -0.00417768164f);
  ps = fmaf(ps, ws, 0.246640727f);
  ps = fmaf(ps, ws, 1.50140941f);
  float pl = -0.000200214257f;
  pl = fmaf(pl, wl, 0.000100950558f);
  pl = fmaf(pl, wl, 0.00134934322f);
  pl = fmaf(pl, wl, -0.00367342844f);
  pl = fmaf(pl, wl, 0.00573950773f);
  pl = fmaf(pl, wl, -0.0076224613f);
  pl = fmaf(pl, wl, 0.00943887047f);
  pl = fmaf(pl, wl, 1.00167406f);
  pl = fmaf(pl, wl, 2.83297682f);
  return (w < 5.0f ? ps : pl) * x;
}

// jax-f32-faithful N(0,1) noise, PARTITIONABLE threefry: counter=(0,g), draw=o0^o1
DEV float noise_at(unsigned g) {
  unsigned o0, o1;
  threefry2x32(0u, g, o0, o1);
  unsigned bits = o0 ^ o1;
  float f = __uint_as_float((bits >> 9) | 0x3f800000u) - 1.0f;
  float u = f * 2.0f - 0.99999994f;
  u = fmaxf(-0.99999994f, u);
  return 1.41421356f * erfinv_xla(u);
}

// ---------- K0: guidance constants c1,c2 (96 x 256 each, f32) ----------
__global__ __launch_bounds__(256) void k_glob(
    const float* __restrict__ gf, const float* __restrict__ gs,
    const float* __restrict__ lng, const float* __restrict__ lnb,
    const float* __restrict__ Wgd, const float* __restrict__ Wout1,
    float* __restrict__ cout) {
  int bq = blockIdx.x >> 1, which = blockIdx.x & 1;
  const float* row = which ? (gs + (size_t)(bq / 12) * DIM) : (gf + (size_t)bq * DIM);
  __shared__ float lx[DIM];
  __shared__ float sg[HID];
  __shared__ double sred[8];
  int tid = threadIdx.x, lane = tid & 63, wv = tid >> 6;
  float v0 = row[tid], v1 = row[tid + 256];
  double s = (double)v0 + v1, q = (double)v0 * v0 + (double)v1 * v1;
  #pragma unroll
  for (int m = 1; m < 64; m <<= 1) { s += __shfl_xor(s, m); q += __shfl_xor(q, m); }
  if (lane == 0) { sred[wv * 2] = s; sred[wv * 2 + 1] = q; }
  __syncthreads();
  double ts = sred[0] + sred[2] + sred[4] + sred[6];
  double tq = sred[1] + sred[3] + sred[5] + sred[7];
  double mean = ts / 512.0;
  double var = tq / 512.0 - mean * mean;
  float mn = (float)mean;
  float rs = (float)(1.0 / sqrt(var + 1e-5));
  lx[tid]       = (v0 - mn) * rs * lng[tid] + lnb[tid];
  lx[tid + 256] = (v1 - mn) * rs * lng[tid + 256] + lnb[tid + 256];
  __syncthreads();
  float acc = 0.0f;
  for (int d = 0; d < DIM; ++d) acc = fmaf(lx[d], Wgd[(size_t)d * HID + tid], acc);
  sg[tid] = gelu32(acc);
  __syncthreads();
  float c = 0.0f;
  for (int j = 0; j < HID; ++j) c = fmaf(sg[j], Wout1[(size_t)(HID + j) * HID + tid], c);
  cout[((size_t)which * BP + bq) * HID + tid] = c;
}

// ---------- K1: fused LN -> GEMM1(gelu) -> GEMM2 -> epilogue -> scores (f32) ----------
__global__ __launch_bounds__(256) void k_fused(
    const float* __restrict__ x,
    const float* __restrict__ g_in, const float* __restrict__ b_in,
    const float* __restrict__ Win, const float* __restrict__ W1,
    const float* __restrict__ W2,
    const float* __restrict__ c1, const float* __restrict__ c2,
    float* __restrict__ scores) {
  __shared__ __align__(16) float xs[RB][DIM];   // 32 KB; reused as loc/red
  __shared__ float stat[RB][2];
  float (*loc)[HID] = (float(*)[HID])xs;        // first 16 KB
  float (*red)[HID] = (float(*)[HID])(&xs[8][0]); // second 16 KB

  const int tid = threadIdx.x, lane = tid & 63, wv = tid >> 6;
  const int gr0 = blockIdx.x * RB;

  // ---- stage x rows (f32) ----
  #pragma unroll
  for (int i = 0; i < 8; ++i) {
    int j = tid + i * 256;              // float4 index, 2048 total
    int row = j >> 7, c4 = (j & 127) << 2;
    *(float4*)&xs[row][c4] = *(const float4*)(x + (size_t)(gr0 + row) * DIM + c4);
  }
  __syncthreads();

  // ---- per-row LN stats (f64, cheap) ----
  #pragma unroll
  for (int rr = 0; rr < 4; ++rr) {
    int row = wv * 4 + rr;
    double s = 0.0, q = 0.0;
    #pragma unroll
    for (int e = 0; e < 8; ++e) {
      double v = (double)xs[row][lane + 64 * e];
      s += v; q += v * v;
    }
    #pragma unroll
    for (int m = 1; m < 64; m <<= 1) { s += __shfl_xor(s, m); q += __shfl_xor(q, m); }
    if (lane == 0) {
      double mean = s / 512.0;
      double var = q / 512.0 - mean * mean;
      stat[row][0] = (float)mean;
      stat[row][1] = (float)(1.0 / sqrt(var + 1e-5));
    }
  }
  __syncthreads();

  // ---- phase B: S1[row] = sum_d x[row][d]*(g[d]*Win[d][tid]); gw,bw alongside ----
  float acc[RB];
  #pragma unroll
  for (int r = 0; r < RB; ++r) acc[r] = 0.0f;
  float gw = 0.0f, bw = 0.0f;
  for (int d0 = 0; d0 < DIM; d0 += 4) {
    float4 xv[RB];
    #pragma unroll
    for (int r = 0; r < RB; ++r) xv[r] = *(const float4*)&xs[r][d0];
    #pragma unroll
    for (int e = 0; e < 4; ++e) {
      int d = d0 + e;
      float wr = Win[(size_t)d * HID + tid];
      float wg = wr * g_in[d];
      gw += wg;
      bw = fmaf(b_in[d], wr, bw);
      #pragma unroll
      for (int r = 0; r < RB; ++r) {
        float xe = (e == 0) ? xv[r].x : (e == 1) ? xv[r].y : (e == 2) ? xv[r].z : xv[r].w;
        acc[r] = fmaf(xe, wg, acc[r]);
      }
    }
  }
  __syncthreads();   // all xs reads done before overwrite

  // ---- local = gelu(rs*S1 - rs*m*gw + bw) ----
  float lv_[RB];
  #pragma unroll
  for (int r = 0; r < RB; ++r) {
    float mn = stat[r][0], rs = stat[r][1];
    lv_[r] = gelu32(rs * acc[r] - rs * mn * gw + bw);
  }
  __syncthreads();
  #pragma unroll
  for (int r = 0; r < RB; ++r) loc[r][tid] = lv_[r];
  __syncthreads();

  // ---- phase C: U[row] = sum_j local[row][j] * W1[j][tid] ----
  float acc2[RB];
  #pragma unroll
  for (int r = 0; r < RB; ++r) acc2[r] = 0.0f;
  for (int j0 = 0; j0 < HID; j0 += 4) {
    float4 lv[RB];
    #pragma unroll
    for (int r = 0; r < RB; ++r) lv[r] = *(const float4*)&loc[r][j0];
    #pragma unroll
    for (int e = 0; e < 4; ++e) {
      float w1 = W1[(size_t)(j0 + e) * HID + tid];
      #pragma unroll
      for (int r = 0; r < RB; ++r) {
        float le = (e == 0) ? lv[r].x : (e == 1) ? lv[r].y : (e == 2) ? lv[r].z : lv[r].w;
        acc2[r] = fmaf(le, w1, acc2[r]);
      }
    }
  }
  __syncthreads();   // loc reads done before red overwrite

  // ---- phase D: s1/s2 reductions and scores ----
  float w2 = W2[tid];
  int bfr = gr0 / NTOK;                 // frame of row gr0 (may advance by 1 inside)
  #pragma unroll
  for (int r = 0; r < RB; ++r) {
    int bf = (gr0 + r) / NTOK;
    red[r & 7][tid] = gelu32(acc2[r] + c1[(size_t)bf * HID + tid]) * w2;
    if ((r & 7) == 7) {
      __syncthreads();
      if (r == 7 ? (wv < 2) : (wv >= 2)) {
        // handled below
      }
      __syncthreads();
    }
  }
  // simpler: recompute per batch of 8 rows with explicit staging
  float s1v[RB], s2v[RB];
  for (int half = 0; half < 2; ++half) {
    #pragma unroll
    for (int rr = 0; rr < 8; ++rr) {
      int r = half * 8 + rr;
      int bf = (gr0 + r) / NTOK;
      red[rr][tid] = gelu32(acc2[r] + c1[(size_t)bf * HID + tid]) * w2;
    }
    __syncthreads();
    #pragma unroll
    for (int rr = 0; rr < 2; ++rr) {
      int row = wv * 2 + rr;
      float s = red[row][lane] + red[row][lane + 64] + red[row][lane + 128] + red[row][lane + 192];
      #pragma unroll
      for (int m = 1; m < 64; m <<= 1) s += __shfl_xor(s, m);
      s1v[half * 8 + row] = s;   // only meaningful on this wave; stored per-thread
    }
    __syncthreads();
    #pragma unroll
    for (int rr = 0; rr < 8; ++rr) {
      int r = half * 8 + rr;
      int bf = (gr0 + r) / NTOK;
      red[rr][tid] = gelu32(acc2[r] + c2[(size_t)bf * HID + tid]) * w2;
    }
    __syncthreads();
    #pragma unroll
    for (int rr = 0; rr < 2; ++rr) {
      int row = wv * 2 + rr;
      float s = red[row][lane] + red[row][lane + 64] + red[row][lane + 128] + red[row][lane + 192];
      #pragma unroll
      for (int m = 1; m < 64; m <<= 1) s += __shfl_xor(s, m);
      s2v[half * 8 + row] = s;
    }
    __syncthreads();
  }
  // write: wave wv owns rows {wv*2, wv*2+1} of each half
  if (lane == 0) {
    #pragma unroll
    for (int half = 0; half < 2; ++half) {
      #pragma unroll
      for (int rr = 0; rr < 2; ++rr) {
        int r = half * 8 + wv * 2 + rr;
        scores[gr0 + r] = tanhf(s1v[r]) + tanhf(s2v[r]);
      }
    }
  }
  (void)bfr;
}

// ---------- K2: perturbed top-k scatter, f32 keys, int counts ----------
__global__ __launch_bounds__(256) void k_topk(const float* __restrict__ scores,
                                              int* __restrict__ cnt) {
  int sid = blockIdx.x * 4 + (threadIdx.x >> 6);  // 0..47999
  int lane = threadIdx.x & 63;
  int b = sid / NS;
  unsigned key[4];
  #pragma unroll
  for (int c = 0; c < 4; ++c) {
    int j = c * 64 + lane;
    if (j < NTOK) {
      float n = noise_at((unsigned)sid * 196u + (unsigned)j);
      float p = fmaf(0.05f, n, scores[b * NTOK + j]);
      unsigned ub = __float_as_uint(p);
      key[c] = (ub & 0x80000000u) ? ~ub : (ub | 0x80000000u);
    } else {
      key[c] = 0u;
    }
  }
  // binary search for the 49th-largest 32-bit key
  unsigned prefix = 0u;
  for (int bit = 31; bit >= 0; --bit) {
    unsigned t = prefix | (1u << bit);
    int cn = 0;
    #pragma unroll
    for (int c = 0; c < 4; ++c) cn += __popcll(__ballot(key[c] >= t));
    if (cn >= TOPK) prefix = t;
  }
  unsigned long long mE[4];
  int cntG = 0;
  #pragma unroll
  for (int c = 0; c < 4; ++c) {
    cntG += __popcll(__ballot(key[c] > prefix));
    mE[c] = __ballot(key[c] == prefix);
  }
  int need = TOPK - cntG;                      // >=1; ties -> lowest index (stable top_k)
  unsigned long long lt = (1ull << lane) - 1ull;
  bool sel[4];
  #pragma unroll
  for (int c = 0; c < 4; ++c) {
    int er = 0;
    for (int cc = 0; cc < c; ++cc) er += __popcll(mE[cc]);
    er += __popcll(mE[c] & lt);
    sel[c] = (key[c] > prefix) || ((key[c] == prefix) && (er < need));
  }
  unsigned long long mS[4];
  #pragma unroll
  for (int c = 0; c < 4; ++c) mS[c] = __ballot(sel[c]);
  int base = 0;
  #pragma unroll
  for (int c = 0; c < 4; ++c) {
    if (sel[c]) {
      int rank = base + __popcll(mS[c] & lt);
      int j = c * 64 + lane;
      atomicAdd(&cnt[((size_t)b * TOPK + rank) * NTOK + j], 1);
    }
    base += __popcll(mS[c]);
  }
}

// ---------- K3: out[b,k,:] = sum_l (cnt/500) * x[b,l,:]  (f32) ----------
__global__ __launch_bounds__(128) void k_out(const float* __restrict__ x,
                                             const int* __restrict__ cnt,
                                             float* __restrict__ out) {
  int bk = blockIdx.x;          // 0..96*49-1
  int b = bk / TOPK;
  __shared__ float sw[NTOK];
  for (int l = threadIdx.x; l < NTOK; l += 128)
    sw[l] = (float)cnt[(size_t)bk * NTOK + l] * 0.002f;
  __syncthreads();
  int d = threadIdx.x * 4;
  float a0 = 0, a1 = 0, a2 = 0, a3 = 0;
  for (int l = 0; l < NTOK; ++l) {
    float w = sw[l];
    if (w != 0.0f) {
      float4 xv = *(const float4*)(x + ((size_t)(b * NTOK + l)) * DIM + d);
      a0 = fmaf(w, xv.x, a0); a1 = fmaf(w, xv.y, a1);
      a2 = fmaf(w, xv.z, a2); a3 = fmaf(w, xv.w, a3);
    }
  }
  float4 o = {a0, a1, a2, a3};
  *(float4*)(out + (size_t)bk * DIM + d) = o;
}

// ---------- launcher ----------
extern "C" void kernel_launch(void* const* d_in, const int* in_sizes, int n_in,
                              void* d_out, int out_size, void* d_ws, size_t ws_size,
                              hipStream_t stream) {
  const float* x       = (const float*)d_in[0];
  const float* gf      = (const float*)d_in[1];
  const float* gs      = (const float*)d_in[2];
  const float* ln_in_g = (const float*)d_in[3];
  const float* ln_in_b = (const float*)d_in[4];
  const float* W_in    = (const float*)d_in[5];
  const float* ln_gd_g = (const float*)d_in[6];
  const float* ln_gd_b = (const float*)d_in[7];
  const float* W_gd    = (const float*)d_in[8];
  const float* W_out1  = (const float*)d_in[9];
  const float* W_out2  = (const float*)d_in[10];
  float* out = (float*)d_out;

  // ws layout (f32/int): c1 | c2 | scores | cnt
  float* c1     = (float*)d_ws;
  float* c2     = c1 + (size_t)BP * HID;
  float* scores = c2 + (size_t)BP * HID;
  int*   cnt    = (int*)(scores + ROWS);

  k_glob<<<192, 256, 0, stream>>>(gf, gs, ln_gd_g, ln_gd_b, W_gd, W_out1, c1);
  k_fused<<<ROWS / RB, 256, 0, stream>>>(x, ln_in_g, ln_in_b, W_in, W_out1, W_out2,
                                         c1, c2, scores);
  hipMemsetAsync(cnt, 0, (size_t)BP * TOPK * NTOK * sizeof(int), stream);
  k_topk<<<(BP * NS) / 4, 256, 0, stream>>>(scores, cnt);
  k_out<<<BP * TOPK, 128, 0, stream>>>(x, cnt, out);
}

// Round 5
// 435.020 us; speedup vs baseline: 1.2469x; 1.1661x over previous
//
#include <hip/hip_runtime.h>
#include <stdint.h>

#define DEV __device__ __forceinline__

// ---------- problem constants ----------
#define BP 96
#define NTOK 196
#define DIM 512
#define HID 256
#define NS 500
#define TOPK 49
#define ROWS (BP * NTOK)          // 18816
#define RB 32                     // rows per fused block

// ---------- math helpers ----------
DEV float gelu32(float v) {
  return 0.5f * v * (1.0f + erff(v * 0.70710678f));
}

// async global->LDS, 16B per lane, wave-uniform LDS base (HW adds lane*16)
DEV void gld_lds16(const float* g, float* l) {
  __builtin_amdgcn_global_load_lds(
      (const __attribute__((address_space(1))) void*)g,
      (__attribute__((address_space(3))) void*)l, 16, 0, 0);
}

// Threefry-2x32, 20 rounds, key = (0, 1)  (jax.random.key(1))
DEV void threefry2x32(uint32_t x0, uint32_t x1, uint32_t& o0, uint32_t& o1) {
  const uint32_t k0 = 0u, k1 = 1u;
  const uint32_t k2 = 0x1BD11BDAu ^ k0 ^ k1;
  x0 += k0; x1 += k1;
#define TF_R(r) { x0 += x1; x1 = (x1 << (r)) | (x1 >> (32 - (r))); x1 ^= x0; }
  TF_R(13) TF_R(15) TF_R(26) TF_R(6)
  x0 += k1; x1 += k2 + 1u;
  TF_R(17) TF_R(29) TF_R(16) TF_R(24)
  x0 += k2; x1 += k0 + 2u;
  TF_R(13) TF_R(15) TF_R(26) TF_R(6)
  x0 += k0; x1 += k1 + 3u;
  TF_R(17) TF_R(29) TF_R(16) TF_R(24)
  x0 += k1; x1 += k2 + 4u;
  TF_R(13) TF_R(15) TF_R(26) TF_R(6)
  x0 += k2; x1 += k0 + 5u;
#undef TF_R
  o0 = x0; o1 = x1;
}

// XLA ErfInv32 (Giles polynomial)
DEV float erfinv_xla(float x) {
  float w = -log1pf(-x * x);
  float ws = w - 2.5f;
  float wl = sqrtf(w) - 3.0f;
  float ps = 2.81022636e-08f;
  ps = fmaf(ps, ws, 3.43273939e-07f);
  ps = fmaf(ps, ws, -3.5233877e-06f);
  ps = fmaf(ps, ws, -4.39150654e-06f);
  ps = fmaf(ps, ws, 0.00021858087f);
  ps = fmaf(ps, ws, -0.00125372503f);
  ps = fmaf(ps, ws, -0.00417768164f);
  ps = fmaf(ps, ws, 0.246640727f);
  ps = fmaf(ps, ws, 1.50140941f);
  float pl = -0.000200214257f;
  pl = fmaf(pl, wl, 0.000100950558f);
  pl = fmaf(pl, wl, 0.00134934322f);
  pl = fmaf(pl, wl, -0.00367342844f);
  pl = fmaf(pl, wl, 0.00573950773f);
  pl = fmaf(pl, wl, -0.0076224613f);
  pl = fmaf(pl, wl, 0.00943887047f);
  pl = fmaf(pl, wl, 1.00167406f);
  pl = fmaf(pl, wl, 2.83297682f);
  return (w < 5.0f ? ps : pl) * x;
}

// jax-f32-faithful N(0,1) noise, PARTITIONABLE threefry: counter=(0,g), draw=o0^o1
DEV float noise_at(unsigned g) {
  unsigned o0, o1;
  threefry2x32(0u, g, o0, o1);
  unsigned bits = o0 ^ o1;
  float f = __uint_as_float((bits >> 9) | 0x3f800000u) - 1.0f;
  float u = f * 2.0f - 0.99999994f;
  u = fmaxf(-0.99999994f, u);
  return 1.41421356f * erfinv_xla(u);
}

// ---------- K0: guidance constants c1,c2 (96 x 256 each, f32) ----------
__global__ __launch_bounds__(256) void k_glob(
    const float* __restrict__ gf, const float* __restrict__ gs,
    const float* __restrict__ lng, const float* __restrict__ lnb,
    const float* __restrict__ Wgd, const float* __restrict__ Wout1,
    float* __restrict__ cout) {
  int bq = blockIdx.x >> 1, which = blockIdx.x & 1;
  const float* row = which ? (gs + (size_t)(bq / 12) * DIM) : (gf + (size_t)bq * DIM);
  __shared__ float lx[DIM];
  __shared__ float sg[HID];
  __shared__ double sred[8];
  int tid = threadIdx.x, lane = tid & 63, wv = tid >> 6;
  float v0 = row[tid], v1 = row[tid + 256];
  double s = (double)v0 + v1, q = (double)v0 * v0 + (double)v1 * v1;
  #pragma unroll
  for (int m = 1; m < 64; m <<= 1) { s += __shfl_xor(s, m); q += __shfl_xor(q, m); }
  if (lane == 0) { sred[wv * 2] = s; sred[wv * 2 + 1] = q; }
  __syncthreads();
  double ts = sred[0] + sred[2] + sred[4] + sred[6];
  double tq = sred[1] + sred[3] + sred[5] + sred[7];
  double mean = ts / 512.0;
  double var = tq / 512.0 - mean * mean;
  float mn = (float)mean;
  float rs = (float)(1.0 / sqrt(var + 1e-5));
  lx[tid]       = (v0 - mn) * rs * lng[tid] + lnb[tid];
  lx[tid + 256] = (v1 - mn) * rs * lng[tid + 256] + lnb[tid + 256];
  __syncthreads();
  float acc = 0.0f;
  for (int d = 0; d < DIM; ++d) acc = fmaf(lx[d], Wgd[(size_t)d * HID + tid], acc);
  sg[tid] = gelu32(acc);
  __syncthreads();
  float c = 0.0f;
  for (int j = 0; j < HID; ++j) c = fmaf(sg[j], Wout1[(size_t)(HID + j) * HID + tid], c);
  cout[((size_t)which * BP + bq) * HID + tid] = c;
}

// ---------- K1: xn = LN(x)*g + b  (memory-bound prepass, f64 stats) ----------
__global__ __launch_bounds__(256) void k_norm(
    const float* __restrict__ x, const float* __restrict__ g,
    const float* __restrict__ b, float* __restrict__ xn) {
  int r = blockIdx.x * 4 + (threadIdx.x >> 6);
  int lane = threadIdx.x & 63;
  const float4* xr = (const float4*)(x + (size_t)r * DIM);
  float4 a = xr[lane], c = xr[lane + 64];
  double s = (double)a.x + a.y + a.z + a.w + (double)c.x + c.y + c.z + c.w;
  double q = (double)a.x * a.x + (double)a.y * a.y + (double)a.z * a.z + (double)a.w * a.w +
             (double)c.x * c.x + (double)c.y * c.y + (double)c.z * c.z + (double)c.w * c.w;
  #pragma unroll
  for (int m = 1; m < 64; m <<= 1) { s += __shfl_xor(s, m); q += __shfl_xor(q, m); }
  double mean = s / 512.0;
  double var = q / 512.0 - mean * mean;
  float mn = (float)mean;
  float rs = (float)(1.0 / sqrt(var + 1e-5));
  float4 g0 = ((const float4*)g)[lane], g1 = ((const float4*)g)[lane + 64];
  float4 b0 = ((const float4*)b)[lane], b1 = ((const float4*)b)[lane + 64];
  float4 o0, o1;
  o0.x = fmaf((a.x - mn) * rs, g0.x, b0.x);
  o0.y = fmaf((a.y - mn) * rs, g0.y, b0.y);
  o0.z = fmaf((a.z - mn) * rs, g0.z, b0.z);
  o0.w = fmaf((a.w - mn) * rs, g0.w, b0.w);
  o1.x = fmaf((c.x - mn) * rs, g1.x, b1.x);
  o1.y = fmaf((c.y - mn) * rs, g1.y, b1.y);
  o1.z = fmaf((c.z - mn) * rs, g1.z, b1.z);
  o1.w = fmaf((c.w - mn) * rs, g1.w, b1.w);
  float4* xo = (float4*)(xn + (size_t)r * DIM);
  xo[lane] = o0;
  xo[lane + 64] = o1;
}

// ---------- K2: fused GEMM1(gelu) -> GEMM2 -> epilogue -> scores ----------
// 256 thr = 8 row-groups x 32 col-groups; thread tile 4 rows x (4+4) cols.
__global__ __launch_bounds__(256) void k_fused(
    const float* __restrict__ xn, const float* __restrict__ Win,
    const float* __restrict__ W1, const float* __restrict__ W2,
    const float* __restrict__ c1, const float* __restrict__ c2,
    float* __restrict__ scores) {
  __shared__ float As[RB][32];     // 4 KB
  __shared__ float Bs[32][HID];    // 32 KB
  __shared__ float loc[RB][HID];   // 32 KB
  const int tid = threadIdx.x;
  const int lane = tid & 63, wv = tid >> 6;
  const int rg = tid >> 5, cg = tid & 31;
  const int r0 = rg * 4, cLo = cg * 4, cHi = cg * 4 + 128;
  const int gr0 = blockIdx.x * RB;

  // ---- phase B: local = gelu(xn @ Win) ----
  float aLo[4][4] = {}, aHi[4][4] = {};
  for (int kc = 0; kc < DIM; kc += 32) {
    __syncthreads();   // prior compute done before overwriting As/Bs
    gld_lds16(xn + (size_t)(gr0 + wv * 8 + (lane >> 3)) * DIM + kc + (lane & 7) * 4,
              &As[wv * 8][0]);
    #pragma unroll
    for (int rr = 0; rr < 8; ++rr) {
      int row = wv * 8 + rr;
      gld_lds16(Win + (size_t)(kc + row) * HID + lane * 4, &Bs[row][0]);
    }
    __syncthreads();   // drains vmcnt
    #pragma unroll
    for (int k = 0; k < 32; ++k) {
      float4 b0 = *(const float4*)&Bs[k][cLo];
      float4 b1 = *(const float4*)&Bs[k][cHi];
      #pragma unroll
      for (int i = 0; i < 4; ++i) {
        float av = As[r0 + i][k];
        aLo[i][0] = fmaf(av, b0.x, aLo[i][0]);
        aLo[i][1] = fmaf(av, b0.y, aLo[i][1]);
        aLo[i][2] = fmaf(av, b0.z, aLo[i][2]);
        aLo[i][3] = fmaf(av, b0.w, aLo[i][3]);
        aHi[i][0] = fmaf(av, b1.x, aHi[i][0]);
        aHi[i][1] = fmaf(av, b1.y, aHi[i][1]);
        aHi[i][2] = fmaf(av, b1.z, aHi[i][2]);
        aHi[i][3] = fmaf(av, b1.w, aHi[i][3]);
      }
    }
  }
  // write local (contiguous per-lane chunks -> conflict-free)
  #pragma unroll
  for (int i = 0; i < 4; ++i) {
    float4 lo, hi;
    lo.x = gelu32(aLo[i][0]); lo.y = gelu32(aLo[i][1]);
    lo.z = gelu32(aLo[i][2]); lo.w = gelu32(aLo[i][3]);
    hi.x = gelu32(aHi[i][0]); hi.y = gelu32(aHi[i][1]);
    hi.z = gelu32(aHi[i][2]); hi.w = gelu32(aHi[i][3]);
    *(float4*)&loc[r0 + i][cLo] = lo;
    *(float4*)&loc[r0 + i][cHi] = hi;
  }

  // ---- phase C: U = loc @ W1 ----
  float uLo[4][4] = {}, uHi[4][4] = {};
  for (int kc = 0; kc < HID; kc += 32) {
    __syncthreads();   // loc writes visible; Bs safe to overwrite
    #pragma unroll
    for (int rr = 0; rr < 8; ++rr) {
      int row = wv * 8 + rr;
      gld_lds16(W1 + (size_t)(kc + row) * HID + lane * 4, &Bs[row][0]);
    }
    __syncthreads();
    #pragma unroll
    for (int k = 0; k < 32; ++k) {
      int kk = kc + k;
      float4 b0 = *(const float4*)&Bs[k][cLo];
      float4 b1 = *(const float4*)&Bs[k][cHi];
      #pragma unroll
      for (int i = 0; i < 4; ++i) {
        float av = loc[r0 + i][kk];
        uLo[i][0] = fmaf(av, b0.x, uLo[i][0]);
        uLo[i][1] = fmaf(av, b0.y, uLo[i][1]);
        uLo[i][2] = fmaf(av, b0.z, uLo[i][2]);
        uLo[i][3] = fmaf(av, b0.w, uLo[i][3]);
        uHi[i][0] = fmaf(av, b1.x, uHi[i][0]);
        uHi[i][1] = fmaf(av, b1.y, uHi[i][1]);
        uHi[i][2] = fmaf(av, b1.z, uHi[i][2]);
        uHi[i][3] = fmaf(av, b1.w, uHi[i][3]);
      }
    }
  }

  // ---- epilogue: per-row score = tanh(s1) + tanh(s2), half-wave reduce ----
  float4 w2lo = *(const float4*)(W2 + cLo);
  float4 w2hi = *(const float4*)(W2 + cHi);
  #pragma unroll
  for (int i = 0; i < 4; ++i) {
    int row = gr0 + r0 + i;
    int bf = row / NTOK;
    const float* c1p = c1 + (size_t)bf * HID;
    const float* c2p = c2 + (size_t)bf * HID;
    float4 c1lo = *(const float4*)(c1p + cLo), c1hi = *(const float4*)(c1p + cHi);
    float4 c2lo = *(const float4*)(c2p + cLo), c2hi = *(const float4*)(c2p + cHi);
    float s1 = gelu32(uLo[i][0] + c1lo.x) * w2lo.x + gelu32(uLo[i][1] + c1lo.y) * w2lo.y +
               gelu32(uLo[i][2] + c1lo.z) * w2lo.z + gelu32(uLo[i][3] + c1lo.w) * w2lo.w +
               gelu32(uHi[i][0] + c1hi.x) * w2hi.x + gelu32(uHi[i][1] + c1hi.y) * w2hi.y +
               gelu32(uHi[i][2] + c1hi.z) * w2hi.z + gelu32(uHi[i][3] + c1hi.w) * w2hi.w;
    float s2 = gelu32(uLo[i][0] + c2lo.x) * w2lo.x + gelu32(uLo[i][1] + c2lo.y) * w2lo.y +
               gelu32(uLo[i][2] + c2lo.z) * w2lo.z + gelu32(uLo[i][3] + c2lo.w) * w2lo.w +
               gelu32(uHi[i][0] + c2hi.x) * w2hi.x + gelu32(uHi[i][1] + c2hi.y) * w2hi.y +
               gelu32(uHi[i][2] + c2hi.z) * w2hi.z + gelu32(uHi[i][3] + c2hi.w) * w2hi.w;
    #pragma unroll
    for (int m = 1; m < 32; m <<= 1) { s1 += __shfl_xor(s1, m); s2 += __shfl_xor(s2, m); }
    if (cg == 0) scores[row] = tanhf(s1) + tanhf(s2);
  }
}

// ---------- K3: perturbed top-k scatter, f32 keys, int counts ----------
__global__ __launch_bounds__(256) void k_topk(const float* __restrict__ scores,
                                              int* __restrict__ cnt) {
  int sid = blockIdx.x * 4 + (threadIdx.x >> 6);  // 0..47999
  int lane = threadIdx.x & 63;
  int b = sid / NS;
  unsigned key[4];
  #pragma unroll
  for (int c = 0; c < 4; ++c) {
    int j = c * 64 + lane;
    if (j < NTOK) {
      float n = noise_at((unsigned)sid * 196u + (unsigned)j);
      float p = fmaf(0.05f, n, scores[b * NTOK + j]);
      unsigned ub = __float_as_uint(p);
      key[c] = (ub & 0x80000000u) ? ~ub : (ub | 0x80000000u);
    } else {
      key[c] = 0u;
    }
  }
  unsigned prefix = 0u;
  for (int bit = 31; bit >= 0; --bit) {
    unsigned t = prefix | (1u << bit);
    int cn = 0;
    #pragma unroll
    for (int c = 0; c < 4; ++c) cn += __popcll(__ballot(key[c] >= t));
    if (cn >= TOPK) prefix = t;
  }
  unsigned long long mE[4];
  int cntG = 0;
  #pragma unroll
  for (int c = 0; c < 4; ++c) {
    cntG += __popcll(__ballot(key[c] > prefix));
    mE[c] = __ballot(key[c] == prefix);
  }
  int need = TOPK - cntG;
  unsigned long long lt = (1ull << lane) - 1ull;
  bool sel[4];
  #pragma unroll
  for (int c = 0; c < 4; ++c) {
    int er = 0;
    for (int cc = 0; cc < c; ++cc) er += __popcll(mE[cc]);
    er += __popcll(mE[c] & lt);
    sel[c] = (key[c] > prefix) || ((key[c] == prefix) && (er < need));
  }
  unsigned long long mS[4];
  #pragma unroll
  for (int c = 0; c < 4; ++c) mS[c] = __ballot(sel[c]);
  int base = 0;
  #pragma unroll
  for (int c = 0; c < 4; ++c) {
    if (sel[c]) {
      int rank = base + __popcll(mS[c] & lt);
      int j = c * 64 + lane;
      atomicAdd(&cnt[((size_t)b * TOPK + rank) * NTOK + j], 1);
    }
    base += __popcll(mS[c]);
  }
}

// ---------- K4: out[b,k,:] = sum_l (cnt/500) * x[b,l,:] ----------
__global__ __launch_bounds__(128) void k_out(const float* __restrict__ x,
                                             const int* __restrict__ cnt,
                                             float* __restrict__ out) {
  int bk = blockIdx.x;
  int b = bk / TOPK;
  __shared__ float sw[NTOK];
  for (int l = threadIdx.x; l < NTOK; l += 128)
    sw[l] = (float)cnt[(size_t)bk * NTOK + l] * 0.002f;
  __syncthreads();
  int d = threadIdx.x * 4;
  float a0 = 0, a1 = 0, a2 = 0, a3 = 0;
  for (int l = 0; l < NTOK; ++l) {
    float w = sw[l];
    if (w != 0.0f) {
      float4 xv = *(const float4*)(x + ((size_t)(b * NTOK + l)) * DIM + d);
      a0 = fmaf(w, xv.x, a0); a1 = fmaf(w, xv.y, a1);
      a2 = fmaf(w, xv.z, a2); a3 = fmaf(w, xv.w, a3);
    }
  }
  float4 o = {a0, a1, a2, a3};
  *(float4*)(out + (size_t)bk * DIM + d) = o;
}

// ---------- launcher ----------
extern "C" void kernel_launch(void* const* d_in, const int* in_sizes, int n_in,
                              void* d_out, int out_size, void* d_ws, size_t ws_size,
                              hipStream_t stream) {
  const float* x       = (const float*)d_in[0];
  const float* gf      = (const float*)d_in[1];
  const float* gs      = (const float*)d_in[2];
  const float* ln_in_g = (const float*)d_in[3];
  const float* ln_in_b = (const float*)d_in[4];
  const float* W_in    = (const float*)d_in[5];
  const float* ln_gd_g = (const float*)d_in[6];
  const float* ln_gd_b = (const float*)d_in[7];
  const float* W_gd    = (const float*)d_in[8];
  const float* W_out1  = (const float*)d_in[9];
  const float* W_out2  = (const float*)d_in[10];
  float* out = (float*)d_out;
  float* ws  = (float*)d_ws;

  // ws layout: xn (ROWS*DIM) | c1 | c2 | scores | cnt   (~42.5 MB total)
  float* xn     = ws;
  float* c1     = ws + (size_t)ROWS * DIM;
  float* c2     = c1 + (size_t)BP * HID;
  float* scores = c2 + (size_t)BP * HID;
  int*   cnt    = (int*)(scores + ROWS);

  k_glob<<<192, 256, 0, stream>>>(gf, gs, ln_gd_g, ln_gd_b, W_gd, W_out1, c1);
  k_norm<<<ROWS / 4, 256, 0, stream>>>(x, ln_in_g, ln_in_b, xn);
  k_fused<<<ROWS / RB, 256, 0, stream>>>(xn, W_in, W_out1, W_out2, c1, c2, scores);
  hipMemsetAsync(cnt, 0, (size_t)BP * TOPK * NTOK * sizeof(int), stream);
  k_topk<<<(BP * NS) / 4, 256, 0, stream>>>(scores, cnt);
  k_out<<<BP * TOPK, 128, 0, stream>>>(x, cnt, out);
}